// Round 10
// baseline (79.587 us; speedup 1.0000x reference)
//
#include <hip/hip_runtime.h>
#include <stdint.h>
#include <math.h>

#define NB 8
#define NQ 512

typedef unsigned long long u64;

// ---- register-array helpers: constant-index-only access (no scratch spills) ----
static __device__ __forceinline__ u64 getw8(const u64 (&a)[8], int w) {
    u64 r = 0ull;
#pragma unroll
    for (int k = 0; k < 8; k++) if (k == w) r = a[k];
    return r;
}
static __device__ __forceinline__ void setbit8(u64 (&a)[8], int c) {
    int w = c >> 6; u64 m = 1ull << (c & 63);
#pragma unroll
    for (int k = 0; k < 8; k++) if (k == w) a[k] |= m;
}
static __device__ __forceinline__ bool getbit8(const u64 (&a)[8], int c) {
    return (getw8(a, c >> 6) >> (c & 63)) & 1ull;
}

// Fused prep+cost: xyxy conversions inline (bit-identical to reference:
// Kalman innovation == 0 exactly, so filtered = (prev*scale)/scale).
__global__ void cost_kernel(const float* __restrict__ prev_boxes,
                            const float* __restrict__ curr_boxes,
                            const float* __restrict__ image_sizes,
                            u64* __restrict__ cost,
                            float* __restrict__ out) {
#pragma clang fp contract(off)
    int t = blockIdx.x * blockDim.x + threadIdx.x;   // 0 .. NB*NQ*NQ-1
    if (t == 0) out[0] = 0.f;
    int b = t >> 18;
    int rem = t & (NQ * NQ - 1);
    int i = rem >> 9;        // row: curr box
    int j = rem & (NQ - 1);  // col: filtered box
    float4 cb = ((const float4*)curr_boxes)[(b << 9) + i];
    float ax = cb.x - 0.5f * cb.z, ay = cb.y - 0.5f * cb.w;
    float az = cb.x + 0.5f * cb.z, aw = cb.y + 0.5f * cb.w;
    float H = image_sizes[2 * b + 0];
    float W = image_sizes[2 * b + 1];
    float4 pb = ((const float4*)prev_boxes)[(b << 9) + j];
    float fcx = (pb.x * W) / W, fcy = (pb.y * H) / H;
    float fw  = (pb.z * W) / W, fh  = (pb.w * H) / H;
    float bx = fcx - 0.5f * fw, by = fcy - 0.5f * fh;
    float bz = fcx + 0.5f * fw, bw = fcy + 0.5f * fh;
    float area_a = (az - ax) * (aw - ay);
    float area_b = (bz - bx) * (bw - by);
    float ltx = fmaxf(ax, bx), lty = fmaxf(ay, by);
    float rbx = fminf(az, bz), rby = fminf(aw, bw);
    float w = fmaxf(rbx - ltx, 0.f), h = fmaxf(rby - lty, 0.f);
    float inter = w * h;
    float uni = area_a + area_b - inter;
    float iou = inter / (uni + 1e-7f);
    float lcx = fminf(ax, bx), lcy = fminf(ay, by);
    float rcx = fmaxf(az, bz), rcy = fmaxf(aw, bw);
    float wc = fmaxf(rcx - lcx, 0.f), hc = fmaxf(rcy - lcy, 0.f);
    float areac = wc * hc;
    float giou = iou - (areac - uni) / (areac + 1e-7f);
    float gl = 1.f - giou;
    u64 m = __ballot(gl < 0.2f);
    if ((threadIdx.x & 63) == 0)
        cost[((size_t)((b << 9) + i)) * 8 + (j >> 6)] = m;
}

// Exact integer replication of the reference JV Hungarian on a {0,1} cost
// matrix + fused CIoU epilogue. R10: 512-thread block — staging, ballot
// precompute (waves 0-7, one word-group each) and the epilogue (1 col per
// thread) are 8-wave parallel; the serial event walk + apB recompute run
// entirely inside wave 0 (R8's verified barrier-free mechanics: Zc
// broadcast via shuffles, 8 serial ballots — no __syncthreads per event).
// Identity-permutation structure: with no holes, row i's cursor column is
// i-1; only rows flagged nz&(col0|diag|ap) need any work. delta>0 or a
// hole falls back to the exact general integer JV.
__global__ __launch_bounds__(512, 1) void hungarian_kernel(
        const u64* __restrict__ cost,
        const float* __restrict__ prev_boxes,
        const float* __restrict__ curr_boxes,
        const float* __restrict__ image_sizes,
        float* __restrict__ out) {
    int b = blockIdx.x;
    int tid = threadIdx.x;
    int lane = tid & 63;
    int wvi = tid >> 6;          // 0..7
    __shared__ __align__(16) u64 costL[NQ * 8];   // 32 KB
    __shared__ int p[NQ + 1];
    __shared__ int wayL[NQ + 1];
    __shared__ int u[NQ + 1];
    __shared__ int vv[NQ + 1];
    __shared__ int minvA[NQ + 1];
    __shared__ unsigned char used[NQ + 1];
    __shared__ u64 nzS[8], c0S[8], dgS[8];

    {
        const ulonglong2* src = (const ulonglong2*)(cost + (size_t)b * NQ * 8);
        ulonglong2* dst = (ulonglong2*)costL;
        for (int k = tid; k < NQ * 4; k += 512) dst[k] = src[k];
    }
    for (int k = tid; k <= NQ; k += 512) { p[k] = k; wayL[k] = 0; u[k] = 0; vv[k] = 0; }
    __syncthreads();

    // 8-wave ballot precompute: wave wvi owns word-group wvi
    {
        const u64* Zr = costL + (((wvi << 6) + lane) << 3);
        u64 o = 0ull;
#pragma unroll
        for (int k = 0; k < 8; k++) o |= Zr[k];
        u64 nzb = __ballot(o != 0ull);
        u64 c0b = __ballot((Zr[0] & 1ull) != 0ull);
        u64 dgb = __ballot(((Zr[wvi] >> lane) & 1ull) != 0ull);
        if (lane == 0) { nzS[wvi] = nzb; c0S[wvi] = c0b; dgS[wvi] = dgb; }
    }
    __syncthreads();

    if (wvi == 0) {
        // wave-0 internal: serial walk on lane 0, apB recompute by all 64 lanes
        u64 nzB[8], c0B[8], dgB[8], apB[8];
#pragma unroll
        for (int k = 0; k < 8; k++) { nzB[k] = nzS[k]; c0B[k] = c0S[k]; dgB[k] = dgS[k]; apB[k] = 0ull; }
        bool ownerNZ0 = false;
        int owner0 = 1;
        u64 Zc[8];
#pragma unroll
        for (int k = 0; k < 8; k++) Zc[k] = 0ull;
        int wIdx = 0;
        u64 bits = 0ull, pendMask = ~0ull;
        bool started = false;

        auto intW = [&](int w) -> u64 {
            u64 x = getw8(c0B, w) | getw8(dgB, w);
            if (ownerNZ0) x |= getw8(apB, w);
            return getw8(nzB, w) & x;
        };
        auto runGeneral = [&](int igen) {
            // exact general integer JV for rows igen..NQ (reference semantics).
            // occupied cols are contiguous 1..igen-1; zero p for free cols so
            // the p[j0]==0 free test works (identity was prewritten).
            for (int j = igen; j <= NQ; j++) p[j] = 0;
            for (int i2 = igen; i2 <= NQ; i2++) {
                p[0] = i2;
                for (int j = 0; j <= NQ; j++) { minvA[j] = 0x7fffffff; used[j] = 0; }
                int j0 = 0;
                while (true) {
                    used[j0] = 1;
                    int i0 = p[j0];
                    int ui0 = u[i0];
                    const u64* rr = costL + ((size_t)(i0 - 1) << 3);
                    int delta = 0x7fffffff, j1 = 0;
                    for (int j = 1; j <= NQ; j++) {
                        if (!used[j]) {
                            int cbit = (int)((rr[(j - 1) >> 6] >> ((j - 1) & 63)) & 1ull);
                            int cur = cbit - ui0 - vv[j];
                            if (cur < minvA[j]) { minvA[j] = cur; wayL[j] = (i2 << 10) | j0; }
                            if (minvA[j] < delta) { delta = minvA[j]; j1 = j; }
                        }
                    }
                    for (int j = 0; j <= NQ; j++) {
                        if (used[j]) { u[p[j]] += delta; vv[j] -= delta; }
                        else minvA[j] -= delta;
                    }
                    j0 = j1;
                    if (p[j0] == 0) break;
                }
                while (j0) {
                    int wv2 = wayL[j0];
                    int jn = ((wv2 >> 10) == i2) ? (wv2 & 1023) : 0;
                    p[j0] = p[jn];
                    j0 = jn;
                }
            }
        };

        for (;;) {   // wave-uniform loop (no block barriers)
            int action = 0;   // 1 = recompute apB (Zc changed), 3 = done
            if (lane == 0) {
                if (!started) {
                    started = true;
                    if (nzB[0] & 1ull) {
                        // row 1 special: col0 is free (cursor=0)
                        u64 Z1[8];
#pragma unroll
                        for (int k = 0; k < 8; k++) Z1[k] = costL[k];
                        if (!(Z1[0] & 1ull)) {
                            owner0 = 1; ownerNZ0 = true;
#pragma unroll
                            for (int k = 0; k < 8; k++) Zc[k] = Z1[k];
                            action = 1; pendMask = ~1ull; wIdx = 0;
                        } else {
                            runGeneral(1); action = 3;
                        }
                    } else {
                        bits = intW(0) & ~1ull;
                    }
                }
                while (action == 0) {
                    if (bits == 0ull) {
                        wIdx++;
                        if (wIdx >= 8) { action = 3; break; }
                        bits = intW(wIdx);
                        continue;
                    }
                    int l = __builtin_ctzll(bits);
                    bits &= bits - 1;
                    u64 rem = (l == 63) ? 0ull : (~0ull << (l + 1));
                    int i = (wIdx << 6) + l + 1;   // 1-based row; cursor col = i-1
                    bool c0 = (getw8(c0B, wIdx) >> l) & 1ull;
                    bool apb = ownerNZ0 && ((getw8(apB, wIdx) >> l) & 1ull);
                    if (!c0 && !apb) {
                        // diag event: relocation (zero owner0) / swap (nz owner0,
                        // ap==0 guarantees Zc[i-1]==0). p[i]=owner0, p[1]=i.
                        p[i] = owner0;
                        p[1] = i;
                        owner0 = i; ownerNZ0 = true;
#pragma unroll
                        for (int k = 0; k < 8; k++) Zc[k] = costL[((i - 1) << 3) + k];
                        action = 1; pendMask = rem;
                    } else {
                        // full bitset search (zero duals)
                        int prevO = owner0; bool prevF = ownerNZ0;
                        bool bail = false, hole = false;
                        u64 Z[8];
#pragma unroll
                        for (int k = 0; k < 8; k++) Z[k] = costL[((i - 1) << 3) + k];
                        u64 ones[8], vis[8], nzA[8], nzBf[8];
#pragma unroll
                        for (int k = 0; k < 8; k++) { ones[k] = Z[k]; vis[k] = 0ull; nzA[k] = 0ull; nzBf[k] = 0ull; }
                        int fA_c = 0, fA_p = 0, fB_c = 0, fB_p = 0;
                        int foldn = 0, assignTo = -1;
                        while (true) {
                            int c2 = -1;
#pragma unroll
                            for (int k = 7; k >= 0; k--) {
                                u64 s = ~ones[k] & ~vis[k];
                                if (s != 0ull) c2 = (k << 6) + __builtin_ctzll(s);
                            }
                            if (c2 < 0) { bail = true; break; }       // delta>0 needed
                            if (c2 >= i - 1) {                        // free region
                                if (c2 == i - 1) assignTo = c2;
                                else hole = true;                     // free above cursor
                                break;
                            }
                            int pc = p[c2 + 1];
                            u64 Zo[8];
#pragma unroll
                            for (int k = 0; k < 8; k++) Zo[k] = costL[((pc - 1) << 3) + k];
                            setbit8(vis, c2);
                            u64 nzv[8], ap2 = 0ull;
#pragma unroll
                            for (int k = 0; k < 8; k++) { nzv[k] = ones[k] & ~Zo[k]; ones[k] &= Zo[k]; ap2 |= ones[k]; }
                            if (foldn == 0) {
                                fA_c = c2; fA_p = pc;
#pragma unroll
                                for (int k = 0; k < 8; k++) nzA[k] = nzv[k];
                            } else if (foldn == 1) {
                                fB_c = c2; fB_p = pc;
#pragma unroll
                                for (int k = 0; k < 8; k++) nzBf[k] = nzv[k];
                            } else {
#pragma unroll
                                for (int k = 0; k < 8; k++) {
                                    u64 tt = nzv[k];
                                    while (tt) { int b2 = __builtin_ctzll(tt); tt &= tt - 1; wayL[(k << 6) + b2 + 1] = (i << 10) | (c2 + 1); }
                                }
                            }
                            foldn++;
                            if (ap2 == 0ull) { assignTo = i - 1; break; }   // shortcut -> cursor
                        }
                        if (bail || hole) {
                            runGeneral(i);
                            action = 3;
                        } else {
                            int cc = assignTo;
                            while (true) {
                                bool inA = getbit8(nzA, cc), inB = getbit8(nzBf, cc);
                                if (inB)      { p[cc + 1] = fB_p; cc = fB_c; }
                                else if (inA) { p[cc + 1] = fA_p; cc = fA_c; }
                                else if (foldn > 2) {
                                    int wv2 = wayL[cc + 1];
                                    if ((wv2 >> 10) == i) { int jn = wv2 & 1023; p[cc + 1] = p[jn]; cc = jn - 1; }
                                    else                  { p[cc + 1] = i; break; }
                                } else { p[cc + 1] = i; break; }
                            }
                            owner0 = p[1];
                            ownerNZ0 = (getw8(nzB, (owner0 - 1) >> 6) >> ((owner0 - 1) & 63)) & 1ull;
                            if (ownerNZ0 && !(prevF && prevO == owner0)) {
#pragma unroll
                                for (int k = 0; k < 8; k++) Zc[k] = costL[((owner0 - 1) << 3) + k];
                                action = 1; pendMask = rem;
                            } else {
                                bits = intW(wIdx) & rem;
                            }
                        }
                    }
                }
            }
            action = __shfl(action, 0, 64);
            if (action == 1) {
                // broadcast Zc from lane 0, wave-internal recompute of apB
                u64 zc[8];
#pragma unroll
                for (int k = 0; k < 8; k++) {
                    int lo = __shfl((int)(Zc[k] & 0xffffffffull), 0, 64);
                    int hi = __shfl((int)(Zc[k] >> 32), 0, 64);
                    zc[k] = (((u64)(unsigned)hi) << 32) | (u64)(unsigned)lo;
                }
#pragma unroll
                for (int w = 0; w < 8; w++) {
                    const u64* Zr = costL + (((w << 6) + lane) << 3);
                    u64 a = 0ull;
#pragma unroll
                    for (int k = 0; k < 8; k++) a |= Zr[k] & zc[k];
                    apB[w] = __ballot(a != 0ull);
                }
                if (lane == 0) {
                    ownerNZ0 = true;
                    bits = intW(wIdx) & pendMask;
                }
                continue;
            }
            break;   // action == 3
        }
    }
    __syncthreads();

    // Fused CIoU epilogue: p is a permutation, so summing over columns j
    // (curr idx j-1, filtered idx p[j]-1) == summing over rows.
    {
#pragma clang fp contract(off)
        float H = image_sizes[2 * b + 0];
        float W = image_sizes[2 * b + 1];
        int j = 1 + tid;          // 1..512
        int r = p[j] - 1;         // filtered row
        int c = j - 1;            // curr box index
        float4 cb = ((const float4*)curr_boxes)[(b << 9) + c];
        float x1 = cb.x - 0.5f * cb.z, y1 = cb.y - 0.5f * cb.w;
        float x2 = cb.x + 0.5f * cb.z, y2 = cb.y + 0.5f * cb.w;
        float4 pb = ((const float4*)prev_boxes)[(b << 9) + r];
        float fcx = (pb.x * W) / W, fcy = (pb.y * H) / H;
        float fw2 = (pb.z * W) / W, fh2 = (pb.w * H) / H;
        float xg1 = fcx - 0.5f * fw2, yg1 = fcy - 0.5f * fh2;
        float xg2 = fcx + 0.5f * fw2, yg2 = fcy + 0.5f * fh2;
        float iw = fmaxf(fminf(x2, xg2) - fmaxf(x1, xg1), 0.f);
        float ih = fmaxf(fminf(y2, yg2) - fmaxf(y1, yg1), 0.f);
        float inter = iw * ih;
        float uni = (x2 - x1) * (y2 - y1) + (xg2 - xg1) * (yg2 - yg1) - inter;
        float iou = inter / (uni + 1e-7f);
        float cw2 = fmaxf(x2, xg2) - fminf(x1, xg1);
        float ch2 = fmaxf(y2, yg2) - fminf(y1, yg1);
        float c2 = cw2 * cw2 + ch2 * ch2 + 1e-7f;
        float dx = ((x1 + x2) - xg1) - xg2;
        float dy = ((y1 + y2) - yg1) - yg2;
        float d2 = (dx * dx + dy * dy) / 4.f;
        const float CC = (float)(4.0 / (M_PI * M_PI));
        float at = atanf((xg2 - xg1) / (yg2 - yg1)) - atanf((x2 - x1) / (y2 - y1));
        float v = CC * (at * at);
        float alpha = v / (((1.f - iou) + v) + 1e-7f);
        float sum = ((1.f - iou) + d2 / c2) + alpha * v;
#pragma unroll
        for (int off = 32; off >= 1; off >>= 1) sum += __shfl_xor(sum, off, 64);
        if (lane == 0) atomicAdd(out, sum * (1.f / 4096.f));
    }
}

extern "C" void kernel_launch(void* const* d_in, const int* in_sizes, int n_in,
                              void* d_out, int out_size, void* d_ws, size_t ws_size,
                              hipStream_t stream) {
    const float* prev_boxes  = (const float*)d_in[0];
    // d_in[1] = prev_logits : dead code (Kalman innovation == 0 exactly)
    const float* curr_boxes  = (const float*)d_in[2];
    const float* image_sizes = (const float*)d_in[3];
    // d_in[4..6] (std weights, log_q_diag) : dead code

    u64* cost = (u64*)d_ws;
    float* out = (float*)d_out;

    cost_kernel<<<(NB * NQ * NQ) / 256, 256, 0, stream>>>(
        prev_boxes, curr_boxes, image_sizes, cost, out);
    hungarian_kernel<<<NB, 512, 0, stream>>>(
        cost, prev_boxes, curr_boxes, image_sizes, out);
}